// Round 10
// baseline (68.635 us; speedup 1.0000x reference)
//
#include <hip/hip_runtime.h>

// ---------------------------------------------------------------------------
// LMU fused cell on MI355X (gfx950).  Round 10: m97-style small blocks.
//   new_h = sigmoid([x|h|m] @ [Wx|Wh|Wm@AT]^T + u*(Wm@BT)^T)
//   new_m = m @ AT^T + u*BT^T     u = [x|h|m].e  (f32 exact, in prep)
// K0 lmu_wpack: weights -> bf16 B-layout [kk][n][8]; Wm2=Wm@AT; wu=Wm@BT.
// K1 lmu_prep:  x|h|m f32 -> one bf16 A-pack [16384][896] + u[16384] f32.
// K2 lmu_gemm:  BM=64 BN=128, 256 thr, LDS 24KB SINGLE-buffered ->
//   4 blocks/CU (16 waves/CU), grid 1024 = 256 M-tiles x 4 N-slices =
//   exactly one residency round. stage -> bar -> mma -> bar per chunk
//   (overlap across 4 co-resident blocks, m97 structure). 14 new_h chunks +
//   4 uniform new_m chunks (A = m-part re-read, B = atpack).
// ---------------------------------------------------------------------------

typedef __bf16 bf16;
typedef bf16  bf16x8 __attribute__((ext_vector_type(8)));
typedef float f32x4  __attribute__((ext_vector_type(4)));
typedef unsigned short u16;

#define BATCH 16384
// ws offsets (u16 units)
#define WPACK 0            // [896/8][512][8] = 458752  (kk>=80 = Wm@AT)
#define ATPACK 458752      // [256/8][256][8] = 65536
#define WUOFF 524288       // 512 f32  (1024 u16)
#define UOFF  525312       // 16384 f32 (32768 u16)
#define APACK 558080       // 16384*896 u16
// end: 15,238,144 u16 = ~30.5 MB

#define PACK_ITEMS 393728  // 327680 + 65536 + 512
#define PACK_BLOCKS 1538
#define WM2_BLOCKS 128

__device__ __forceinline__ u16 f2bf(float f) {
  unsigned u = __builtin_bit_cast(unsigned, f);
  u += 0x7FFFu + ((u >> 16) & 1u);   // RNE
  return (u16)(u >> 16);
}

__device__ __forceinline__ void gload16(const u16* g, u16* l) {
  __builtin_amdgcn_global_load_lds(
      (const __attribute__((address_space(1))) unsigned int*)g,
      (__attribute__((address_space(3))) unsigned int*)l, 16, 0, 0);
}

// ---------------- K0: merged weight prep (validated R8/R9) ------------------
__global__ __launch_bounds__(256) void lmu_wpack(
    const float* __restrict__ Wx, const float* __restrict__ Wh,
    const float* __restrict__ Wm, const float* __restrict__ AT,
    const float* __restrict__ BT, u16* __restrict__ ws) {
  __shared__ float wmt[16 * 256];
  const int bx = blockIdx.x;
  if (bx < PACK_BLOCKS) {
    int i = bx * 256 + threadIdx.x;
    if (i < 327680) {                     // Wall^T[k][n], k<640
      int j = i & 7, rest = i >> 3;
      int n = rest & 511, kk = rest >> 9;
      int k = kk * 8 + j;
      float v = (k < 128) ? Wx[n * 128 + k] : Wh[n * 512 + (k - 128)];
      ws[WPACK + i] = f2bf(v);
    } else if (i < 393216) {              // atpack[kk][d][j] = AT[d][kk*8+j]
      int t = i - 327680;
      int j = t & 7, rest = t >> 3;
      int d = rest & 255, kk = rest >> 8;
      ws[ATPACK + t] = f2bf(AT[d * 256 + kk * 8 + j]);
    } else if (i < PACK_ITEMS) {          // wu[n] = dot(Wm[n,:], BT)
      int n = i - 393216;
      float s = 0.f;
      for (int k = 0; k < 256; k += 4) {
        float4 wv = *(const float4*)(Wm + (size_t)n * 256 + k);
        float4 bv = *(const float4*)(BT + k);
        s += wv.x * bv.x + wv.y * bv.y + wv.z * bv.z + wv.w * bv.w;
      }
      ((float*)(ws + WUOFF))[n] = s;
    }
  } else {                                // Wm2 = Wm @ AT (16r x 64d tiles)
    const int wq = bx - PACK_BLOCKS;
    const int t = threadIdx.x;
    const int nb = (wq & 31) * 16, db = (wq >> 5) * 64;
#pragma unroll
    for (int it = 0; it < 4; ++it) {
      int f = it * 256 + t;
      float4 v = *(const float4*)(Wm + (size_t)(nb + (f >> 6)) * 256 + (f & 63) * 4);
      *(float4*)(wmt + (f >> 6) * 256 + (f & 63) * 4) = v;
    }
    __syncthreads();
    const int d = db + (t & 63);
    const int nn = (t >> 6) * 4;
    float acc[4] = {0.f, 0.f, 0.f, 0.f};
    for (int k = 0; k < 256; ++k) {
      float atv = AT[(size_t)k * 256 + d];
#pragma unroll
      for (int i2 = 0; i2 < 4; ++i2) acc[i2] += wmt[(nn + i2) * 256 + k] * atv;
    }
    const int kk = 80 + (d >> 3), j = d & 7;
#pragma unroll
    for (int i2 = 0; i2 < 4; ++i2)
      ws[WPACK + ((size_t)kk * 512 + (nb + nn + i2)) * 8 + j] = f2bf(acc[i2]);
  }
}

// ---------------- K1: A-pack [row][896] bf16 + u (f32 exact, validated) -----
__global__ __launch_bounds__(256) void lmu_prep(
    const float* __restrict__ x, const float* __restrict__ h,
    const float* __restrict__ m, const float* __restrict__ ex,
    const float* __restrict__ eh, const float* __restrict__ em,
    u16* __restrict__ ws) {
  const int lane = threadIdx.x & 63;
  const int row  = blockIdx.x * 4 + (threadIdx.x >> 6);
  u16* ap = ws + APACK + (size_t)row * 896;
  float s = 0.f;
#pragma unroll
  for (int j = 0; j < 4; ++j) {
    int slot = j * 64 + lane;
    if (slot < 224) {
      float4 a, e;
      if (slot < 32)       { int c = slot * 4;
        a = *(const float4*)(x + (size_t)row * 128 + c); e = *(const float4*)(ex + c); }
      else if (slot < 160) { int c = (slot - 32) * 4;
        a = *(const float4*)(h + (size_t)row * 512 + c); e = *(const float4*)(eh + c); }
      else                 { int c = (slot - 160) * 4;
        a = *(const float4*)(m + (size_t)row * 256 + c); e = *(const float4*)(em + c); }
      s += a.x * e.x + a.y * e.y + a.z * e.z + a.w * e.w;
      unsigned long long pk =
          (unsigned long long)f2bf(a.x)
        | ((unsigned long long)f2bf(a.y) << 16)
        | ((unsigned long long)f2bf(a.z) << 32)
        | ((unsigned long long)f2bf(a.w) << 48);
      *(unsigned long long*)(ap + slot * 4) = pk;
    }
  }
#pragma unroll
  for (int d = 1; d < 64; d <<= 1) s += __shfl_xor(s, d);
  if (lane == 0) ((float*)(ws + UOFF))[row] = s;
}

// ---------------- K2: main GEMM ----------------------------------------------
// grid 1024 = 256 M-tiles x 4 N-slices; 256 thr (4 waves: 2M x 2N).
// LDS 24KB single-buffered: A [8kb][64r][8] = 4096 u16, B [8kk][128n][8] = 8192.
__global__ __launch_bounds__(256, 4) void lmu_gemm(
    const u16* __restrict__ ws, const float* __restrict__ BT,
    float* __restrict__ out) {
  __shared__ __align__(16) u16 smem[12288];
  const int tid  = threadIdx.x;
  const int lane = tid & 63;
  const int w    = tid >> 6;     // 0..3
  const int wr   = w >> 1;       // 0..1 : 32-row slice
  const int wc   = w & 1;        // 0..1 : 64-col (new_h) / 32-col (new_m)
  const int lm   = lane & 15;
  const int kg   = lane >> 4;
  // 4 N-slices of one M-tile at adjacent slots on one XCD
  const int bid  = blockIdx.x;
  const int xcd  = bid & 7;
  const int r8   = bid >> 3;               // 0..127
  const int nsl  = r8 & 3;                 // 0..3
  const int mt_  = xcd * 32 + (r8 >> 2);   // 0..255
  const int b0   = mt_ * 64;

  const u16* wpk = ws + WPACK;
  const u16* atp = ws + ATPACK;
  const u16* ap  = ws + APACK;

  f32x4 acc[2][4];    // new_h: 32r x 64c per wave
  f32x4 acc2[2][2];   // new_m: 32r x 32c per wave
#pragma unroll
  for (int mt = 0; mt < 2; ++mt) {
#pragma unroll
    for (int ct = 0; ct < 4; ++ct) acc[mt][ct] = (f32x4){0.f, 0.f, 0.f, 0.f};
#pragma unroll
    for (int ct = 0; ct < 2; ++ct) acc2[mt][ct] = (f32x4){0.f, 0.f, 0.f, 0.f};
  }

  auto stageA = [&](int koff) {            // 64r x 64k -> [kb][r][8]
#pragma unroll
    for (int ph = 0; ph < 2; ++ph) {
      int i = ph * 256 + tid;
      int kb = i >> 6, r = i & 63;
      gload16(ap + (size_t)(b0 + r) * 896 + koff + kb * 8, smem + i * 8);
    }
  };
  auto stageBh = [&](int c) {              // [kk][128n][8]
#pragma unroll
    for (int ph = 0; ph < 4; ++ph) {
      int i = ph * 256 + tid;
      int kk = i >> 7, n = i & 127;
      gload16(wpk + ((size_t)(c * 8 + kk) * 512 + nsl * 128 + n) * 8,
              smem + 4096 + i * 8);
    }
  };
  auto stageBm = [&](int cm) {             // [kk][64n dup][8]
#pragma unroll
    for (int ph = 0; ph < 4; ++ph) {
      int i = ph * 256 + tid;
      int kk = i >> 7, n = i & 63;
      gload16(atp + ((size_t)(cm * 8 + kk) * 256 + nsl * 64 + n) * 8,
              smem + 4096 + i * 8);
    }
  };
  auto mma_h = [&]() {
#pragma unroll
    for (int ks = 0; ks < 2; ++ks) {
      const int kq = ks * 4 + kg;
      bf16x8 a[2];
#pragma unroll
      for (int mt = 0; mt < 2; ++mt)
        a[mt] = *(const bf16x8*)(smem + (kq * 64 + wr * 32 + mt * 16 + lm) * 8);
#pragma unroll
      for (int ct = 0; ct < 4; ++ct) {
        bf16x8 b = *(const bf16x8*)(smem + 4096 + (kq * 128 + wc * 64 + ct * 16 + lm) * 8);
#pragma unroll
        for (int mt = 0; mt < 2; ++mt)
          acc[mt][ct] = __builtin_amdgcn_mfma_f32_16x16x32_bf16(a[mt], b, acc[mt][ct], 0, 0, 0);
      }
    }
  };
  auto mma_m = [&]() {
#pragma unroll
    for (int ks = 0; ks < 2; ++ks) {
      const int kq = ks * 4 + kg;
      bf16x8 a[2];
#pragma unroll
      for (int mt = 0; mt < 2; ++mt)
        a[mt] = *(const bf16x8*)(smem + (kq * 64 + wr * 32 + mt * 16 + lm) * 8);
#pragma unroll
      for (int ct = 0; ct < 2; ++ct) {
        bf16x8 b = *(const bf16x8*)(smem + 4096 + (kq * 128 + wc * 32 + ct * 16 + lm) * 8);
#pragma unroll
        for (int mt = 0; mt < 2; ++mt)
          acc2[mt][ct] = __builtin_amdgcn_mfma_f32_16x16x32_bf16(a[mt], b, acc2[mt][ct], 0, 0, 0);
      }
    }
  };

  // ---- 14 new_h chunks (m97 structure: stage -> bar -> mma -> bar) ----
#pragma unroll 2
  for (int c = 0; c < 14; ++c) {
    stageA(c * 64);
    stageBh(c);
    __syncthreads();
    mma_h();
    __syncthreads();
  }
  // ---- 4 new_m chunks (A = m-part re-read, B = atpack) ----
#pragma unroll 2
  for (int cm = 0; cm < 4; ++cm) {
    stageA(640 + cm * 64);
    stageBm(cm);
    __syncthreads();
    mma_m();
    __syncthreads();
  }

  // ---- epilogue ----
  const float* uf  = (const float*)(ws + UOFF);
  const float* wuf = (const float*)(ws + WUOFF);
  float wuv[4], btv[2];
#pragma unroll
  for (int ct = 0; ct < 4; ++ct) wuv[ct] = wuf[nsl * 128 + wc * 64 + ct * 16 + lm];
#pragma unroll
  for (int ct = 0; ct < 2; ++ct) btv[ct] = BT[nsl * 64 + wc * 32 + ct * 16 + lm];
  float* outm = out + (size_t)BATCH * 512;
#pragma unroll
  for (int mt = 0; mt < 2; ++mt)
#pragma unroll
    for (int j = 0; j < 4; ++j) {
      int rl = wr * 32 + mt * 16 + kg * 4 + j;
      size_t row = (size_t)(b0 + rl);
      float uv = uf[row];
#pragma unroll
      for (int ct = 0; ct < 4; ++ct) {
        float v = acc[mt][ct][j] + uv * wuv[ct];
        out[row * 512 + nsl * 128 + wc * 64 + ct * 16 + lm] = 1.0f / (1.0f + __expf(-v));
      }
#pragma unroll
      for (int ct = 0; ct < 2; ++ct)
        outm[row * 256 + nsl * 64 + wc * 32 + ct * 16 + lm] = acc2[mt][ct][j] + uv * btv[ct];
    }
}

extern "C" void kernel_launch(void* const* d_in, const int* in_sizes, int n_in,
                              void* d_out, int out_size, void* d_ws, size_t ws_size,
                              hipStream_t stream) {
  const float* x  = (const float*)d_in[0];
  const float* h  = (const float*)d_in[1];
  const float* m  = (const float*)d_in[2];
  const float* Wx = (const float*)d_in[3];
  const float* Wh = (const float*)d_in[4];
  const float* Wm = (const float*)d_in[5];
  const float* ex = (const float*)d_in[6];
  const float* eh = (const float*)d_in[7];
  const float* em = (const float*)d_in[8];
  const float* AT = (const float*)d_in[9];
  const float* BT = (const float*)d_in[10];
  float* out = (float*)d_out;
  u16* ws = (u16*)d_ws;   // uses ~30.5 MB

  lmu_wpack<<<PACK_BLOCKS + WM2_BLOCKS, 256, 0, stream>>>(Wx, Wh, Wm, AT, BT, ws);
  lmu_prep<<<BATCH / 4, 256, 0, stream>>>(x, h, m, ex, eh, em, ws);
  lmu_gemm<<<1024, 256, 0, stream>>>(ws, BT, out);
}

// Round 11
// 66.811 us; speedup vs baseline: 1.0273x; 1.0273x over previous
//
#include <hip/hip_runtime.h>

// ---------------------------------------------------------------------------
// LMU fused cell on MI355X (gfx950).  Round 11: m97-clone 128x128 tile.
//   new_h = sigmoid([x|h|m] @ [Wx|Wh|Wm@AT]^T + u*(Wm@BT)^T)
//   new_m = m @ AT^T + u*BT^T     u = [x|h|m].e  (f32 exact, in prep)
// K0 lmu_wpack: weights -> bf16 B-layout [kk][n][8]; Wm2=Wm@AT; wu=Wm@BT.
// K1 lmu_prep:  x|h|m f32 -> one bf16 A-pack [16384][896] + u[16384] f32.
// K2 lmu_gemm:  BM=128 BN=128, 256 thr / 4 waves, wave = 64x64 (4x4 frags,
//   32 MFMA per barrier-pair), BK=64, LDS 32KB single-buffered,
//   grid 512 = 128 M-tiles x 4 N-slices = 2 blocks/CU, one round.
//   14 new_h chunks + 4 uniform new_m chunks (B = atpack 64-col slice).
// ---------------------------------------------------------------------------

typedef __bf16 bf16;
typedef bf16  bf16x8 __attribute__((ext_vector_type(8)));
typedef float f32x4  __attribute__((ext_vector_type(4)));
typedef unsigned short u16;

#define BATCH 16384
// ws offsets (u16 units)
#define WPACK 0            // [896/8][512][8] = 458752  (kk>=80 = Wm@AT)
#define ATPACK 458752      // [256/8][256][8] = 65536
#define WUOFF 524288       // 512 f32  (1024 u16)
#define UOFF  525312       // 16384 f32 (32768 u16)
#define APACK 558080       // 16384*896 u16
// end: 15,238,144 u16 = ~30.5 MB

#define PACK_ITEMS 393728  // 327680 + 65536 + 512
#define PACK_BLOCKS 1538
#define WM2_BLOCKS 128

__device__ __forceinline__ u16 f2bf(float f) {
  unsigned u = __builtin_bit_cast(unsigned, f);
  u += 0x7FFFu + ((u >> 16) & 1u);   // RNE
  return (u16)(u >> 16);
}

__device__ __forceinline__ void gload16(const u16* g, u16* l) {
  __builtin_amdgcn_global_load_lds(
      (const __attribute__((address_space(1))) unsigned int*)g,
      (__attribute__((address_space(3))) unsigned int*)l, 16, 0, 0);
}

// ---------------- K0: merged weight prep (validated R8-R10) -----------------
__global__ __launch_bounds__(256) void lmu_wpack(
    const float* __restrict__ Wx, const float* __restrict__ Wh,
    const float* __restrict__ Wm, const float* __restrict__ AT,
    const float* __restrict__ BT, u16* __restrict__ ws) {
  __shared__ float wmt[16 * 256];
  const int bx = blockIdx.x;
  if (bx < PACK_BLOCKS) {
    int i = bx * 256 + threadIdx.x;
    if (i < 327680) {                     // Wall^T[k][n], k<640
      int j = i & 7, rest = i >> 3;
      int n = rest & 511, kk = rest >> 9;
      int k = kk * 8 + j;
      float v = (k < 128) ? Wx[n * 128 + k] : Wh[n * 512 + (k - 128)];
      ws[WPACK + i] = f2bf(v);
    } else if (i < 393216) {              // atpack[kk][d][j] = AT[d][kk*8+j]
      int t = i - 327680;
      int j = t & 7, rest = t >> 3;
      int d = rest & 255, kk = rest >> 8;
      ws[ATPACK + t] = f2bf(AT[d * 256 + kk * 8 + j]);
    } else if (i < PACK_ITEMS) {          // wu[n] = dot(Wm[n,:], BT)
      int n = i - 393216;
      float s = 0.f;
      for (int k = 0; k < 256; k += 4) {
        float4 wv = *(const float4*)(Wm + (size_t)n * 256 + k);
        float4 bv = *(const float4*)(BT + k);
        s += wv.x * bv.x + wv.y * bv.y + wv.z * bv.z + wv.w * bv.w;
      }
      ((float*)(ws + WUOFF))[n] = s;
    }
  } else {                                // Wm2 = Wm @ AT (16r x 64d tiles)
    const int wq = bx - PACK_BLOCKS;
    const int t = threadIdx.x;
    const int nb = (wq & 31) * 16, db = (wq >> 5) * 64;
#pragma unroll
    for (int it = 0; it < 4; ++it) {
      int f = it * 256 + t;
      float4 v = *(const float4*)(Wm + (size_t)(nb + (f >> 6)) * 256 + (f & 63) * 4);
      *(float4*)(wmt + (f >> 6) * 256 + (f & 63) * 4) = v;
    }
    __syncthreads();
    const int d = db + (t & 63);
    const int nn = (t >> 6) * 4;
    float acc[4] = {0.f, 0.f, 0.f, 0.f};
    for (int k = 0; k < 256; ++k) {
      float atv = AT[(size_t)k * 256 + d];
#pragma unroll
      for (int i2 = 0; i2 < 4; ++i2) acc[i2] += wmt[(nn + i2) * 256 + k] * atv;
    }
    const int kk = 80 + (d >> 3), j = d & 7;
#pragma unroll
    for (int i2 = 0; i2 < 4; ++i2)
      ws[WPACK + ((size_t)kk * 512 + (nb + nn + i2)) * 8 + j] = f2bf(acc[i2]);
  }
}

// ---------------- K1: A-pack [row][896] bf16 + u (f32 exact, validated) -----
__global__ __launch_bounds__(256) void lmu_prep(
    const float* __restrict__ x, const float* __restrict__ h,
    const float* __restrict__ m, const float* __restrict__ ex,
    const float* __restrict__ eh, const float* __restrict__ em,
    u16* __restrict__ ws) {
  const int lane = threadIdx.x & 63;
  const int row  = blockIdx.x * 4 + (threadIdx.x >> 6);
  u16* ap = ws + APACK + (size_t)row * 896;
  float s = 0.f;
#pragma unroll
  for (int j = 0; j < 4; ++j) {
    int slot = j * 64 + lane;
    if (slot < 224) {
      float4 a, e;
      if (slot < 32)       { int c = slot * 4;
        a = *(const float4*)(x + (size_t)row * 128 + c); e = *(const float4*)(ex + c); }
      else if (slot < 160) { int c = (slot - 32) * 4;
        a = *(const float4*)(h + (size_t)row * 512 + c); e = *(const float4*)(eh + c); }
      else                 { int c = (slot - 160) * 4;
        a = *(const float4*)(m + (size_t)row * 256 + c); e = *(const float4*)(em + c); }
      s += a.x * e.x + a.y * e.y + a.z * e.z + a.w * e.w;
      unsigned long long pk =
          (unsigned long long)f2bf(a.x)
        | ((unsigned long long)f2bf(a.y) << 16)
        | ((unsigned long long)f2bf(a.z) << 32)
        | ((unsigned long long)f2bf(a.w) << 48);
      *(unsigned long long*)(ap + slot * 4) = pk;
    }
  }
#pragma unroll
  for (int d = 1; d < 64; d <<= 1) s += __shfl_xor(s, d);
  if (lane == 0) ((float*)(ws + UOFF))[row] = s;
}

// ---------------- K2: main GEMM ----------------------------------------------
// grid 512 = 128 M-tiles x 4 N-slices; 256 thr, 4 waves (2M x 2N), 64x64/wave.
// LDS 32KB single-buffered: A [8kb][128r][8] = 8192 u16, B [8kk][128n][8] = 8192.
__global__ __launch_bounds__(256, 2) void lmu_gemm(
    const u16* __restrict__ ws, const float* __restrict__ BT,
    float* __restrict__ out) {
  __shared__ __align__(16) u16 smem[16384];
  const int tid  = threadIdx.x;
  const int lane = tid & 63;
  const int w    = tid >> 6;     // 0..3
  const int wr   = w >> 1;       // 0..1 : 64-row half
  const int wc   = w & 1;        // 0..1 : 64-col half
  const int lm   = lane & 15;
  const int kg   = lane >> 4;
  // 4 N-slices of one M-tile 8 bids apart -> same XCD, adjacent dispatch
  const int bid  = blockIdx.x;
  const int xcd  = bid & 7;
  const int q    = bid >> 3;               // 0..63
  const int nsl  = q & 3;                  // 0..3
  const int mi   = xcd * 16 + (q >> 2);    // 0..127
  const int b0   = mi * 128;

  const u16* wpk = ws + WPACK;
  const u16* atp = ws + ATPACK;
  const u16* ap  = ws + APACK;

  f32x4 acc[4][4];    // new_h: wave 64r x 64c
  f32x4 acc2[4][2];   // new_m: wave 64r x 32c
#pragma unroll
  for (int mt = 0; mt < 4; ++mt) {
#pragma unroll
    for (int ct = 0; ct < 4; ++ct) acc[mt][ct] = (f32x4){0.f, 0.f, 0.f, 0.f};
#pragma unroll
    for (int ct = 0; ct < 2; ++ct) acc2[mt][ct] = (f32x4){0.f, 0.f, 0.f, 0.f};
  }

  auto stageA = [&](int koff) {            // 128r x 64k -> [kb][r][8]
#pragma unroll
    for (int ph = 0; ph < 4; ++ph) {
      int i = ph * 256 + tid;
      int kb = i >> 7, r = i & 127;
      gload16(ap + (size_t)(b0 + r) * 896 + koff + kb * 8, smem + i * 8);
    }
  };
  auto stageBh = [&](int c) {              // [kk][128n][8]
#pragma unroll
    for (int ph = 0; ph < 4; ++ph) {
      int i = ph * 256 + tid;
      int kk = i >> 7, n = i & 127;
      gload16(wpk + ((size_t)(c * 8 + kk) * 512 + nsl * 128 + n) * 8,
              smem + 8192 + i * 8);
    }
  };
  auto stageBm = [&](int cm) {             // [kk][64n][8]
#pragma unroll
    for (int ph = 0; ph < 2; ++ph) {
      int i = ph * 256 + tid;
      int kk = i >> 6, n = i & 63;
      gload16(atp + ((size_t)(cm * 8 + kk) * 256 + nsl * 64 + n) * 8,
              smem + 8192 + i * 8);
    }
  };
  auto mma_h = [&]() {
#pragma unroll
    for (int ks = 0; ks < 2; ++ks) {
      const int kq = ks * 4 + kg;
      bf16x8 a[4], b[4];
#pragma unroll
      for (int mt = 0; mt < 4; ++mt)
        a[mt] = *(const bf16x8*)(smem + (kq * 128 + wr * 64 + mt * 16 + lm) * 8);
#pragma unroll
      for (int ct = 0; ct < 4; ++ct)
        b[ct] = *(const bf16x8*)(smem + 8192 + (kq * 128 + wc * 64 + ct * 16 + lm) * 8);
#pragma unroll
      for (int mt = 0; mt < 4; ++mt)
#pragma unroll
        for (int ct = 0; ct < 4; ++ct)
          acc[mt][ct] = __builtin_amdgcn_mfma_f32_16x16x32_bf16(a[mt], b[ct], acc[mt][ct], 0, 0, 0);
    }
  };
  auto mma_m = [&]() {
#pragma unroll
    for (int ks = 0; ks < 2; ++ks) {
      const int kq = ks * 4 + kg;
      bf16x8 a[4], b[2];
#pragma unroll
      for (int mt = 0; mt < 4; ++mt)
        a[mt] = *(const bf16x8*)(smem + (kq * 128 + wr * 64 + mt * 16 + lm) * 8);
#pragma unroll
      for (int ct = 0; ct < 2; ++ct)
        b[ct] = *(const bf16x8*)(smem + 8192 + (kq * 64 + wc * 32 + ct * 16 + lm) * 8);
#pragma unroll
      for (int mt = 0; mt < 4; ++mt)
#pragma unroll
        for (int ct = 0; ct < 2; ++ct)
          acc2[mt][ct] = __builtin_amdgcn_mfma_f32_16x16x32_bf16(a[mt], b[ct], acc2[mt][ct], 0, 0, 0);
    }
  };

  // ---- 14 new_h chunks: stage -> bar -> mma -> bar (m97 structure) ----
#pragma unroll 2
  for (int c = 0; c < 14; ++c) {
    stageA(c * 64);
    stageBh(c);
    __syncthreads();
    mma_h();
    __syncthreads();
  }
  // ---- 4 new_m chunks (A = m-part re-read, B = atpack 64-col slice) ----
#pragma unroll 2
  for (int cm = 0; cm < 4; ++cm) {
    stageA(640 + cm * 64);
    stageBm(cm);
    __syncthreads();
    mma_m();
    __syncthreads();
  }

  // ---- epilogue ----
  const float* uf  = (const float*)(ws + UOFF);
  const float* wuf = (const float*)(ws + WUOFF);
  float wuv[4], btv[2];
#pragma unroll
  for (int ct = 0; ct < 4; ++ct) wuv[ct] = wuf[nsl * 128 + wc * 64 + ct * 16 + lm];
#pragma unroll
  for (int ct = 0; ct < 2; ++ct) btv[ct] = BT[nsl * 64 + wc * 32 + ct * 16 + lm];
  float* outm = out + (size_t)BATCH * 512;
#pragma unroll
  for (int mt = 0; mt < 4; ++mt)
#pragma unroll
    for (int j = 0; j < 4; ++j) {
      int rl = wr * 64 + mt * 16 + kg * 4 + j;
      size_t row = (size_t)(b0 + rl);
      float uv = uf[row];
#pragma unroll
      for (int ct = 0; ct < 4; ++ct) {
        float v = acc[mt][ct][j] + uv * wuv[ct];
        out[row * 512 + nsl * 128 + wc * 64 + ct * 16 + lm] = 1.0f / (1.0f + __expf(-v));
      }
#pragma unroll
      for (int ct = 0; ct < 2; ++ct)
        outm[row * 256 + nsl * 64 + wc * 32 + ct * 16 + lm] = acc2[mt][ct][j] + uv * btv[ct];
    }
}

extern "C" void kernel_launch(void* const* d_in, const int* in_sizes, int n_in,
                              void* d_out, int out_size, void* d_ws, size_t ws_size,
                              hipStream_t stream) {
  const float* x  = (const float*)d_in[0];
  const float* h  = (const float*)d_in[1];
  const float* m  = (const float*)d_in[2];
  const float* Wx = (const float*)d_in[3];
  const float* Wh = (const float*)d_in[4];
  const float* Wm = (const float*)d_in[5];
  const float* ex = (const float*)d_in[6];
  const float* eh = (const float*)d_in[7];
  const float* em = (const float*)d_in[8];
  const float* AT = (const float*)d_in[9];
  const float* BT = (const float*)d_in[10];
  float* out = (float*)d_out;
  u16* ws = (u16*)d_ws;   // uses ~30.5 MB

  lmu_wpack<<<PACK_BLOCKS + WM2_BLOCKS, 256, 0, stream>>>(Wx, Wh, Wm, AT, BT, ws);
  lmu_prep<<<BATCH / 4, 256, 0, stream>>>(x, h, m, ex, eh, em, ws);
  lmu_gemm<<<512, 256, 0, stream>>>(ws, BT, out);
}